// Round 1
// baseline (1052.052 us; speedup 1.0000x reference)
//
#include <hip/hip_runtime.h>
#include <hip/hip_bf16.h>
#include <cstddef>

typedef __attribute__((ext_vector_type(4))) float f32x4;
typedef __attribute__((ext_vector_type(8))) short s16x8;

#define B_    64
#define T_    512
#define EMB_  512
#define HID_  1024
#define ENC_  1024
#define VSZ_  32000
#define PRED_N (B_ * VSZ_)

__device__ __forceinline__ unsigned short f2bf(float f) {
  __hip_bfloat16 h = __float2bfloat16(f);
  return __builtin_bit_cast(unsigned short, h);
}

__device__ __forceinline__ s16x8 pack8(f32x4 lo, f32x4 hi) {
  s16x8 r;
  r[0] = (short)f2bf(lo[0]); r[1] = (short)f2bf(lo[1]);
  r[2] = (short)f2bf(lo[2]); r[3] = (short)f2bf(lo[3]);
  r[4] = (short)f2bf(hi[0]); r[5] = (short)f2bf(hi[1]);
  r[6] = (short)f2bf(hi[2]); r[7] = (short)f2bf(hi[3]);
  return r;
}

// ---------------- K1a: embedding gather ----------------
__global__ void k1a_emb(const int* __restrict__ tok, const float* __restrict__ emb,
                        float* __restrict__ x2, unsigned short* __restrict__ xcat) {
  int b = blockIdx.x;
  int t = tok[b];
  for (int c = threadIdx.x; c < EMB_; c += blockDim.x) {
    float e = emb[(size_t)t * EMB_ + c];
    x2[b * 1536 + c] = e;                       // x2 = [e(512) | ctx(1024)]
    xcat[b * 2560 + 2048 + c] = f2bf(e);        // xcat = [h_new | ctx | e] bf16
  }
}

// ---------------- K1: small row-dot GEMV: out[b][r] = bias(+bias2) + h0[b]·W[r,:1024]
// grid (N/16, 64), block 256 = 16 groups x 16 lanes
__global__ void k1_rowdot(const float* __restrict__ W, int ldw,
                          const float* __restrict__ bias, const float* __restrict__ bias2,
                          const float* __restrict__ h0, float* __restrict__ out, int N) {
  __shared__ float hs[HID_];
  int b = blockIdx.y;
  for (int i = threadIdx.x; i < HID_; i += 256) hs[i] = h0[b * HID_ + i];
  __syncthreads();
  int g = threadIdx.x >> 4, ln = threadIdx.x & 15;
  int r = blockIdx.x * 16 + g;
  const float* wr = W + (size_t)r * ldw;
  float acc = 0.f;
  for (int k = ln * 4; k < HID_; k += 64) {
    f32x4 w4 = *(const f32x4*)(wr + k);
    f32x4 h4 = *(const f32x4*)(hs + k);
    acc += w4[0] * h4[0] + w4[1] * h4[1] + w4[2] * h4[2] + w4[3] * h4[3];
  }
  acc += __shfl_xor(acc, 1);
  acc += __shfl_xor(acc, 2);
  acc += __shfl_xor(acc, 4);
  acc += __shfl_xor(acc, 8);
  if (ln == 0) {
    float bs = bias[r] + (bias2 ? bias2[r] : 0.f);
    out[(size_t)b * N + r] = acc + bs;
  }
}

// ---------------- K2: energy GEMM + tanh + v-dot fused -> scores ----------------
// scores[row] += sum_h vW[h] * tanh( enc[row,:]@We[h,:] + hW[b][h] )   (row = b*512+t)
// 128x128x(K=32) tile, bf16 MFMA 16x16x32, reg-staged f32->bf16.
__global__ __launch_bounds__(256, 2) void k2_scores(
    const float* __restrict__ enc, const float* __restrict__ attnW,
    const float* __restrict__ hW, const float* __restrict__ vW,
    float* __restrict__ scores) {
  __shared__ unsigned short As[128][32];
  __shared__ unsigned short Bs[128][32];
  const int tid = threadIdx.x;
  const int rb = blockIdx.x;   // 0..255 row block (M)
  const int cb = blockIdx.y;   // 0..7   col block (h)
  const int wave = tid >> 6, lane = tid & 63;
  const int wr = (wave >> 1) * 64, wc = (wave & 1) * 64;
  const int l16 = lane & 15, l4 = lane >> 4;
  const int row0 = rb * 128, h0 = cb * 128;
  const int srow = tid >> 1, soff = (tid & 1) * 16;

  const float* ag = enc + (size_t)(row0 + srow) * ENC_ + soff;
  const float* bg = attnW + (size_t)(h0 + srow) * 2048 + HID_ + soff;

  f32x4 acc[4][4] = {};

  for (int kt = 0; kt < ENC_ / 32; ++kt) {
    f32x4 a0 = *(const f32x4*)(ag + 0);
    f32x4 a1 = *(const f32x4*)(ag + 4);
    f32x4 a2 = *(const f32x4*)(ag + 8);
    f32x4 a3 = *(const f32x4*)(ag + 12);
    f32x4 b0 = *(const f32x4*)(bg + 0);
    f32x4 b1 = *(const f32x4*)(bg + 4);
    f32x4 b2 = *(const f32x4*)(bg + 8);
    f32x4 b3 = *(const f32x4*)(bg + 12);
    ag += 32; bg += 32;
    s16x8 av0 = pack8(a0, a1), av1 = pack8(a2, a3);
    s16x8 bv0 = pack8(b0, b1), bv1 = pack8(b2, b3);
    __syncthreads();
    *(s16x8*)&As[srow][soff]     = av0;
    *(s16x8*)&As[srow][soff + 8] = av1;
    *(s16x8*)&Bs[srow][soff]     = bv0;
    *(s16x8*)&Bs[srow][soff + 8] = bv1;
    __syncthreads();
    s16x8 af[4], bf[4];
#pragma unroll
    for (int m = 0; m < 4; ++m) af[m] = *(const s16x8*)&As[wr + m * 16 + l16][l4 * 8];
#pragma unroll
    for (int n = 0; n < 4; ++n) bf[n] = *(const s16x8*)&Bs[wc + n * 16 + l16][l4 * 8];
#pragma unroll
    for (int m = 0; m < 4; ++m)
#pragma unroll
      for (int n = 0; n < 4; ++n)
        acc[m][n] = __builtin_amdgcn_mfma_f32_16x16x32_bf16(af[m], bf[n], acc[m][n], 0, 0, 0);
  }

  // epilogue: + hW, tanh, * v, reduce 16 cols, atomicAdd partial score
  const float* hWb = hW + (size_t)(rb >> 2) * HID_;   // 128 rows always within one b
  float vv[4], hb[4];
#pragma unroll
  for (int n = 0; n < 4; ++n) {
    int hcol = h0 + wc + n * 16 + l16;
    vv[n] = vW[hcol];
    hb[n] = hWb[hcol];
  }
#pragma unroll
  for (int m = 0; m < 4; ++m) {
#pragma unroll
    for (int j = 0; j < 4; ++j) {
      float p = 0.f;
#pragma unroll
      for (int n = 0; n < 4; ++n)
        p += vv[n] * tanhf(acc[m][n][j] + hb[n]);
      p += __shfl_xor(p, 1);
      p += __shfl_xor(p, 2);
      p += __shfl_xor(p, 4);
      p += __shfl_xor(p, 8);
      if (l16 == 0)
        atomicAdd(&scores[row0 + wr + m * 16 + l4 * 4 + j], p);
    }
  }
}

// ---------------- K3a: softmax over T per batch row (1 wave / row) ----------------
__global__ void k3a_softmax(const float* __restrict__ scores, float* __restrict__ weights) {
  int b = blockIdx.x, lane = threadIdx.x;
  float s[8];
  float mx = -3.4e38f;
#pragma unroll
  for (int i = 0; i < 8; ++i) { s[i] = scores[b * T_ + lane + i * 64]; mx = fmaxf(mx, s[i]); }
#pragma unroll
  for (int off = 1; off < 64; off <<= 1) mx = fmaxf(mx, __shfl_xor(mx, off));
  float sum = 0.f;
#pragma unroll
  for (int i = 0; i < 8; ++i) { s[i] = expf(s[i] - mx); sum += s[i]; }
#pragma unroll
  for (int off = 1; off < 64; off <<= 1) sum += __shfl_xor(sum, off);
  float inv = 1.f / sum;
#pragma unroll
  for (int i = 0; i < 8; ++i) weights[b * T_ + lane + i * 64] = s[i] * inv;
}

// ---------------- K3b: ctx[b,col] = sum_t w[b,t] * enc[b,t,col] ----------------
__global__ void k3b_ctx(const float* __restrict__ weights, const float* __restrict__ enc,
                        float* __restrict__ x2, unsigned short* __restrict__ xcat) {
  __shared__ float w[T_];
  int b = blockIdx.x >> 2;
  int col = (blockIdx.x & 3) * 256 + threadIdx.x;
  for (int i = threadIdx.x; i < T_; i += 256) w[i] = weights[b * T_ + i];
  __syncthreads();
  const float* e = enc + (size_t)b * T_ * ENC_ + col;
  float a0 = 0, a1 = 0, a2 = 0, a3 = 0;
  for (int t = 0; t < T_; t += 4) {
    a0 += w[t]     * e[(size_t)t * ENC_];
    a1 += w[t + 1] * e[(size_t)(t + 1) * ENC_];
    a2 += w[t + 2] * e[(size_t)(t + 2) * ENC_];
    a3 += w[t + 3] * e[(size_t)(t + 3) * ENC_];
  }
  float acc = (a0 + a1) + (a2 + a3);
  x2[b * 1536 + 512 + col] = acc;
  xcat[b * 2560 + 1024 + col] = f2bf(acc);
}

// ---------------- K4: gates[b][j] = hWhh[b][j] + x2[b]·W_ih[j,:1536] ----------------
// 64x64 tile fp32, grid = 64 j-blocks
__global__ __launch_bounds__(256) void k4_gates(
    const float* __restrict__ x2, const float* __restrict__ Wih,
    const float* __restrict__ hWhh, float* __restrict__ gates) {
  __shared__ float Ws[64][36];
  __shared__ float Xs[64][36];
  const int tid = threadIdx.x;
  const int jb = blockIdx.x;
  const int j0 = (tid & 15) * 4, b0 = (tid >> 4) * 4;
  const int row = tid >> 2, c0 = (tid & 3) * 8;
  const float* wg = Wih + (size_t)(jb * 64 + row) * 1536 + c0;
  const float* xg = x2 + (size_t)row * 1536 + c0;
  float acc[4][4] = {{0.f}};
  for (int kt = 0; kt < 48; ++kt) {
    f32x4 w0 = *(const f32x4*)(wg);
    f32x4 w1 = *(const f32x4*)(wg + 4);
    f32x4 x0 = *(const f32x4*)(xg);
    f32x4 x1 = *(const f32x4*)(xg + 4);
    wg += 32; xg += 32;
    __syncthreads();
    *(f32x4*)&Ws[row][c0]     = w0;
    *(f32x4*)&Ws[row][c0 + 4] = w1;
    *(f32x4*)&Xs[row][c0]     = x0;
    *(f32x4*)&Xs[row][c0 + 4] = x1;
    __syncthreads();
#pragma unroll
    for (int k4 = 0; k4 < 8; ++k4) {
      f32x4 wv[4], xv[4];
#pragma unroll
      for (int i = 0; i < 4; ++i) wv[i] = *(const f32x4*)&Ws[j0 + i][k4 * 4];
#pragma unroll
      for (int l = 0; l < 4; ++l) xv[l] = *(const f32x4*)&Xs[b0 + l][k4 * 4];
#pragma unroll
      for (int i = 0; i < 4; ++i)
#pragma unroll
        for (int l = 0; l < 4; ++l)
          acc[i][l] += wv[i][0] * xv[l][0] + wv[i][1] * xv[l][1] +
                       wv[i][2] * xv[l][2] + wv[i][3] * xv[l][3];
    }
  }
#pragma unroll
  for (int i = 0; i < 4; ++i)
#pragma unroll
    for (int l = 0; l < 4; ++l) {
      int j = jb * 64 + j0 + i, bb = b0 + l;
      gates[(size_t)bb * 4096 + j] = acc[i][l] + hWhh[(size_t)bb * 4096 + j];
    }
}

// ---------------- K4b: LSTM pointwise -> h_new, c_new, xcat ----------------
__global__ void k4b_lstm(const float* __restrict__ gates, const float* __restrict__ cin,
                         float* __restrict__ out, unsigned short* __restrict__ xcat) {
  int b = blockIdx.x;
  for (int j = threadIdx.x; j < HID_; j += blockDim.x) {
    float ig = gates[(size_t)b * 4096 + j];
    float fg = gates[(size_t)b * 4096 + 1024 + j];
    float gg = gates[(size_t)b * 4096 + 2048 + j];
    float og = gates[(size_t)b * 4096 + 3072 + j];
    float i = 1.f / (1.f + expf(-ig));
    float f = 1.f / (1.f + expf(-fg));
    float g = tanhf(gg);
    float o = 1.f / (1.f + expf(-og));
    float c0 = cin[(size_t)b * 1024 + j];
    float cn = f * c0 + i * g;
    float hn = o * tanhf(cn);
    out[PRED_N + (size_t)b * 1024 + j] = hn;
    out[PRED_N + 65536 + (size_t)b * 1024 + j] = cn;
    xcat[b * 2560 + j] = f2bf(hn);
  }
}

// ---------------- K5: pred = xcat(bf16) @ fc_W.T + fc_b ----------------
// 64x128 tile, bf16 MFMA; fc_W cvt'd f32->bf16 on stage (memory-bound on fc_W)
__global__ __launch_bounds__(256, 2) void k5_pred(
    const unsigned short* __restrict__ xcat, const float* __restrict__ fcW,
    const float* __restrict__ fcb, float* __restrict__ pred) {
  __shared__ unsigned short As[64][32];
  __shared__ unsigned short Bs[128][32];
  const int tid = threadIdx.x;
  const int cb = blockIdx.x;   // 0..249
  const int wave = tid >> 6, lane = tid & 63;
  const int wr = (wave >> 1) * 32, wc = (wave & 1) * 64;
  const int l16 = lane & 15, l4 = lane >> 4;
  const int v0 = cb * 128;
  const int arow = tid >> 2, aoff = (tid & 3) * 8;
  const int brow = tid >> 1, boff = (tid & 1) * 16;

  const unsigned short* ag = xcat + (size_t)arow * 2560 + aoff;
  const float* bg = fcW + (size_t)(v0 + brow) * 2560 + boff;

  f32x4 acc[2][4] = {};

  for (int kt = 0; kt < 2560 / 32; ++kt) {
    s16x8 av = *(const s16x8*)(ag);
    ag += 32;
    f32x4 b0 = *(const f32x4*)(bg + 0);
    f32x4 b1 = *(const f32x4*)(bg + 4);
    f32x4 b2 = *(const f32x4*)(bg + 8);
    f32x4 b3 = *(const f32x4*)(bg + 12);
    bg += 32;
    s16x8 bv0 = pack8(b0, b1), bv1 = pack8(b2, b3);
    __syncthreads();
    *(s16x8*)&As[arow][aoff]     = av;
    *(s16x8*)&Bs[brow][boff]     = bv0;
    *(s16x8*)&Bs[brow][boff + 8] = bv1;
    __syncthreads();
    s16x8 af[2], bf[4];
#pragma unroll
    for (int m = 0; m < 2; ++m) af[m] = *(const s16x8*)&As[wr + m * 16 + l16][l4 * 8];
#pragma unroll
    for (int n = 0; n < 4; ++n) bf[n] = *(const s16x8*)&Bs[wc + n * 16 + l16][l4 * 8];
#pragma unroll
    for (int m = 0; m < 2; ++m)
#pragma unroll
      for (int n = 0; n < 4; ++n)
        acc[m][n] = __builtin_amdgcn_mfma_f32_16x16x32_bf16(af[m], bf[n], acc[m][n], 0, 0, 0);
  }
#pragma unroll
  for (int n = 0; n < 4; ++n) {
    int v = v0 + wc + n * 16 + l16;
    float fb = fcb[v];
#pragma unroll
    for (int m = 0; m < 2; ++m) {
      int br = wr + m * 16 + l4 * 4;
#pragma unroll
      for (int j = 0; j < 4; ++j)
        pred[(size_t)(br + j) * VSZ_ + v] = acc[m][n][j] + fb;
    }
  }
}

extern "C" void kernel_launch(void* const* d_in, const int* in_sizes, int n_in,
                              void* d_out, int out_size, void* d_ws, size_t ws_size,
                              hipStream_t stream) {
  (void)in_sizes; (void)n_in; (void)out_size; (void)ws_size;
  const int*   tok   = (const int*)  d_in[0];
  const float* h     = (const float*)d_in[1];
  const float* c     = (const float*)d_in[2];
  const float* enc   = (const float*)d_in[3];
  const float* emb   = (const float*)d_in[4];
  const float* attnW = (const float*)d_in[5];
  const float* attnb = (const float*)d_in[6];
  const float* vW    = (const float*)d_in[7];
  const float* Wih   = (const float*)d_in[8];
  const float* Whh   = (const float*)d_in[9];
  const float* bih   = (const float*)d_in[10];
  const float* bhh   = (const float*)d_in[11];
  const float* fcW   = (const float*)d_in[12];
  const float* fcb   = (const float*)d_in[13];
  float* out = (float*)d_out;

  float* scores  = (float*)d_ws;                 // 32768
  float* weights = scores + 32768;               // 32768
  float* hW      = weights + 32768;              // 64*1024
  float* hWhh    = hW + 64 * 1024;               // 64*4096
  float* x2      = hWhh + 64 * 4096;             // 64*1536  [e | ctx]
  float* gates   = x2 + 64 * 1536;               // 64*4096
  unsigned short* xcat = (unsigned short*)(gates + 64 * 4096);  // 64*2560 bf16

  hipMemsetAsync(scores, 0, 32768 * sizeof(float), stream);
  k1a_emb<<<64, 128, 0, stream>>>(tok, emb, x2, xcat);
  k1_rowdot<<<dim3(64, 64), 256, 0, stream>>>(attnW, 2048, attnb, nullptr, h, hW, 1024);
  k1_rowdot<<<dim3(256, 64), 256, 0, stream>>>(Whh, 1024, bih, bhh, h, hWhh, 4096);
  k2_scores<<<dim3(256, 8), 256, 0, stream>>>(enc, attnW, hW, vW, scores);
  k3a_softmax<<<64, 64, 0, stream>>>(scores, weights);
  k3b_ctx<<<256, 256, 0, stream>>>(weights, enc, x2, xcat);
  k4_gates<<<64, 256, 0, stream>>>(x2, Wih, hWhh, gates);
  k4b_lstm<<<64, 256, 0, stream>>>(gates, c, out, xcat);
  k5_pred<<<250, 256, 0, stream>>>(xcat, fcW, fcb, out);
}

// Round 3
// 1013.600 us; speedup vs baseline: 1.0379x; 1.0379x over previous
//
#include <hip/hip_runtime.h>
#include <hip/hip_bf16.h>
#include <cstddef>

typedef __attribute__((ext_vector_type(4))) float f32x4;
typedef __attribute__((ext_vector_type(8))) short s16x8;

#define B_    64
#define T_    512
#define EMB_  512
#define HID_  1024
#define ENC_  1024
#define VSZ_  32000
#define PRED_N (B_ * VSZ_)

__device__ __forceinline__ unsigned short f2bf(float f) {
  __hip_bfloat16 h = __float2bfloat16(f);
  return __builtin_bit_cast(unsigned short, h);
}

__device__ __forceinline__ s16x8 pack8(f32x4 lo, f32x4 hi) {
  s16x8 r;
  r[0] = (short)f2bf(lo[0]); r[1] = (short)f2bf(lo[1]);
  r[2] = (short)f2bf(lo[2]); r[3] = (short)f2bf(lo[3]);
  r[4] = (short)f2bf(hi[0]); r[5] = (short)f2bf(hi[1]);
  r[6] = (short)f2bf(hi[2]); r[7] = (short)f2bf(hi[3]);
  return r;
}

// XOR slot swizzle: tile row stride = 64B = 4 slots of 16B.
// bank-quad = (4*row + slot') mod 8; slot' = slot ^ ((row>>1)&3) makes any
// 16-lane column-slice read AND the staging writes exactly 2-way (free).
__device__ __forceinline__ int swz(int row, int s) {
  return row * 64 + ((s ^ ((row >> 1) & 3)) << 4);
}

// ---------------- K1a: embedding gather ----------------
__global__ void k1a_emb(const int* __restrict__ tok, const float* __restrict__ emb,
                        float* __restrict__ x2, unsigned short* __restrict__ xcat) {
  int b = blockIdx.x;
  int t = tok[b];
  for (int c = threadIdx.x; c < EMB_; c += blockDim.x) {
    float e = emb[(size_t)t * EMB_ + c];
    x2[b * 1536 + c] = e;                       // x2 = [e(512) | ctx(1024)]
    xcat[b * 2560 + 2048 + c] = f2bf(e);        // xcat = [h_new | ctx | e] bf16
  }
}

// ---------------- K1: small row-dot GEMV ----------------
__global__ void k1_rowdot(const float* __restrict__ W, int ldw,
                          const float* __restrict__ bias, const float* __restrict__ bias2,
                          const float* __restrict__ h0, float* __restrict__ out, int N) {
  __shared__ float hs[HID_];
  int b = blockIdx.y;
  for (int i = threadIdx.x; i < HID_; i += 256) hs[i] = h0[b * HID_ + i];
  __syncthreads();
  int g = threadIdx.x >> 4, ln = threadIdx.x & 15;
  int r = blockIdx.x * 16 + g;
  const float* wr = W + (size_t)r * ldw;
  float acc = 0.f;
  for (int k = ln * 4; k < HID_; k += 64) {
    f32x4 w4 = *(const f32x4*)(wr + k);
    f32x4 h4 = *(const f32x4*)(hs + k);
    acc += w4[0] * h4[0] + w4[1] * h4[1] + w4[2] * h4[2] + w4[3] * h4[3];
  }
  acc += __shfl_xor(acc, 1);
  acc += __shfl_xor(acc, 2);
  acc += __shfl_xor(acc, 4);
  acc += __shfl_xor(acc, 8);
  if (ln == 0) {
    float bs = bias[r] + (bias2 ? bias2[r] : 0.f);
    out[(size_t)b * N + r] = acc + bs;
  }
}

// ---------------- K2: energy GEMM + tanh + v-dot fused -> scores ----------------
// 128x128 tile, K=1024 in 32-steps. Reg-staged 2-deep prefetch, double-buffered
// swizzled LDS, 1 barrier per K-step.
#define K2_LOAD(S, kt) { const float* _pa = ag0 + (kt) * 32;                 \
    S##a0 = *(const f32x4*)(_pa);      S##a1 = *(const f32x4*)(_pa + 4);     \
    S##a2 = *(const f32x4*)(_pa + 8);  S##a3 = *(const f32x4*)(_pa + 12);    \
    const float* _pb = bg0 + (kt) * 32;                                      \
    S##b0 = *(const f32x4*)(_pb);      S##b1 = *(const f32x4*)(_pb + 4);     \
    S##b2 = *(const f32x4*)(_pb + 8);  S##b3 = *(const f32x4*)(_pb + 12); }

#define K2_PW(S, L) {                                                        \
    s16x8 _v0 = pack8(S##a0, S##a1), _v1 = pack8(S##a2, S##a3);              \
    s16x8 _w0 = pack8(S##b0, S##b1), _w1 = pack8(S##b2, S##b3);              \
    *(s16x8*)((L) + waA0) = _v0; *(s16x8*)((L) + waA1) = _v1;                \
    *(s16x8*)((L) + waB0) = _w0; *(s16x8*)((L) + waB1) = _w1; }

#define K2_COMP(L) {                                                         \
    s16x8 af[4], bf[4];                                                      \
    _Pragma("unroll")                                                        \
    for (int m = 0; m < 4; ++m) af[m] = *(const s16x8*)((L) + raA[m]);       \
    _Pragma("unroll")                                                        \
    for (int n = 0; n < 4; ++n) bf[n] = *(const s16x8*)((L) + raB[n]);       \
    _Pragma("unroll")                                                        \
    for (int m = 0; m < 4; ++m)                                              \
      _Pragma("unroll")                                                      \
      for (int n = 0; n < 4; ++n)                                            \
        acc[m][n] = __builtin_amdgcn_mfma_f32_16x16x32_bf16(af[m], bf[n], acc[m][n], 0, 0, 0); }

__global__ __launch_bounds__(256, 2) void k2_scores(
    const float* __restrict__ enc, const float* __restrict__ attnW,
    const float* __restrict__ hW, const float* __restrict__ vW,
    float* __restrict__ scores) {
  __shared__ unsigned char lds0[16384];   // A [0,8192) | B [8192,16384)
  __shared__ unsigned char lds1[16384];
  const int tid = threadIdx.x;
  const int rb = blockIdx.x;   // 0..255 row block (M)
  const int cb = blockIdx.y;   // 0..7   col block (h)
  const int wave = tid >> 6, lane = tid & 63;
  const int wr = (wave >> 1) * 64, wc = (wave & 1) * 64;
  const int l16 = lane & 15, l4 = lane >> 4;
  const int row0 = rb * 128, h0 = cb * 128;
  const int srow = tid >> 1;
  const int s0 = (tid & 1) * 2;

  const float* ag0 = enc   + (size_t)(row0 + srow) * ENC_  + (tid & 1) * 16;
  const float* bg0 = attnW + (size_t)(h0  + srow) * 2048 + HID_ + (tid & 1) * 16;

  const int waA0 = swz(srow, s0), waA1 = swz(srow, s0 + 1);
  const int waB0 = 8192 + waA0,   waB1 = 8192 + waA1;
  int raA[4], raB[4];
#pragma unroll
  for (int m = 0; m < 4; ++m) raA[m] = swz(wr + m * 16 + l16, l4);
#pragma unroll
  for (int n = 0; n < 4; ++n) raB[n] = 8192 + swz(wc + n * 16 + l16, l4);

  f32x4 Xa0, Xa1, Xa2, Xa3, Xb0, Xb1, Xb2, Xb3;
  f32x4 Ya0, Ya1, Ya2, Ya3, Yb0, Yb1, Yb2, Yb3;
  f32x4 acc[4][4] = {};

  K2_LOAD(X, 0);
  K2_PW(X, lds0);
  K2_LOAD(Y, 1);
  __syncthreads();

  for (int kt2 = 0; kt2 < 16; ++kt2) {
    // even step: tile 2*kt2 in lds0
    if (kt2 < 15) K2_LOAD(X, 2 * kt2 + 2);
    K2_COMP(lds0);
    K2_PW(Y, lds1);                       // tile 2*kt2+1
    __syncthreads();
    // odd step: tile 2*kt2+1 in lds1
    if (kt2 < 15) K2_LOAD(Y, 2 * kt2 + 3);
    K2_COMP(lds1);
    if (kt2 < 15) K2_PW(X, lds0);         // tile 2*kt2+2
    __syncthreads();
  }

  // epilogue: + hW, tanh, * v, reduce 16 cols, atomicAdd partial score
  const float* hWb = hW + (size_t)(rb >> 2) * HID_;
  float vv[4], hb[4];
#pragma unroll
  for (int n = 0; n < 4; ++n) {
    int hcol = h0 + wc + n * 16 + l16;
    vv[n] = vW[hcol];
    hb[n] = hWb[hcol];
  }
#pragma unroll
  for (int m = 0; m < 4; ++m) {
#pragma unroll
    for (int j = 0; j < 4; ++j) {
      float p = 0.f;
#pragma unroll
      for (int n = 0; n < 4; ++n)
        p += vv[n] * tanhf(acc[m][n][j] + hb[n]);
      p += __shfl_xor(p, 1);
      p += __shfl_xor(p, 2);
      p += __shfl_xor(p, 4);
      p += __shfl_xor(p, 8);
      if (l16 == 0)
        atomicAdd(&scores[row0 + wr + m * 16 + l4 * 4 + j], p);
    }
  }
}

// ---------------- K3a: softmax over T per batch row ----------------
__global__ void k3a_softmax(const float* __restrict__ scores, float* __restrict__ weights) {
  int b = blockIdx.x, lane = threadIdx.x;
  float s[8];
  float mx = -3.4e38f;
#pragma unroll
  for (int i = 0; i < 8; ++i) { s[i] = scores[b * T_ + lane + i * 64]; mx = fmaxf(mx, s[i]); }
#pragma unroll
  for (int off = 1; off < 64; off <<= 1) mx = fmaxf(mx, __shfl_xor(mx, off));
  float sum = 0.f;
#pragma unroll
  for (int i = 0; i < 8; ++i) { s[i] = expf(s[i] - mx); sum += s[i]; }
#pragma unroll
  for (int off = 1; off < 64; off <<= 1) sum += __shfl_xor(sum, off);
  float inv = 1.f / sum;
#pragma unroll
  for (int i = 0; i < 8; ++i) weights[b * T_ + lane + i * 64] = s[i] * inv;
}

// ---------------- K3b: ctx[b,col] = sum_t w[b,t] * enc[b,t,col] ----------------
__global__ void k3b_ctx(const float* __restrict__ weights, const float* __restrict__ enc,
                        float* __restrict__ x2, unsigned short* __restrict__ xcat) {
  __shared__ float w[T_];
  int b = blockIdx.x >> 2;
  int col = (blockIdx.x & 3) * 256 + threadIdx.x;
  for (int i = threadIdx.x; i < T_; i += 256) w[i] = weights[b * T_ + i];
  __syncthreads();
  const float* e = enc + (size_t)b * T_ * ENC_ + col;
  float a0 = 0, a1 = 0, a2 = 0, a3 = 0, a4 = 0, a5 = 0, a6 = 0, a7 = 0;
  for (int t = 0; t < T_; t += 8) {
    a0 += w[t]     * e[(size_t)t * ENC_];
    a1 += w[t + 1] * e[(size_t)(t + 1) * ENC_];
    a2 += w[t + 2] * e[(size_t)(t + 2) * ENC_];
    a3 += w[t + 3] * e[(size_t)(t + 3) * ENC_];
    a4 += w[t + 4] * e[(size_t)(t + 4) * ENC_];
    a5 += w[t + 5] * e[(size_t)(t + 5) * ENC_];
    a6 += w[t + 6] * e[(size_t)(t + 6) * ENC_];
    a7 += w[t + 7] * e[(size_t)(t + 7) * ENC_];
  }
  float acc = ((a0 + a1) + (a2 + a3)) + ((a4 + a5) + (a6 + a7));
  x2[b * 1536 + 512 + col] = acc;
  xcat[b * 2560 + 1024 + col] = f2bf(acc);
}

// ---------------- K4: gates[b][j] = hWhh[b][j] + x2[b]·W_ih[j,:1536] ----------------
__global__ __launch_bounds__(256) void k4_gates(
    const float* __restrict__ x2, const float* __restrict__ Wih,
    const float* __restrict__ hWhh, float* __restrict__ gates) {
  __shared__ float Ws[64][36];
  __shared__ float Xs[64][36];
  const int tid = threadIdx.x;
  const int jb = blockIdx.x;
  const int j0 = (tid & 15) * 4, b0 = (tid >> 4) * 4;
  const int row = tid >> 2, c0 = (tid & 3) * 8;
  const float* wg = Wih + (size_t)(jb * 64 + row) * 1536 + c0;
  const float* xg = x2 + (size_t)row * 1536 + c0;
  float acc[4][4] = {{0.f}};
  for (int kt = 0; kt < 48; ++kt) {
    f32x4 w0 = *(const f32x4*)(wg);
    f32x4 w1 = *(const f32x4*)(wg + 4);
    f32x4 x0 = *(const f32x4*)(xg);
    f32x4 x1 = *(const f32x4*)(xg + 4);
    wg += 32; xg += 32;
    __syncthreads();
    *(f32x4*)&Ws[row][c0]     = w0;
    *(f32x4*)&Ws[row][c0 + 4] = w1;
    *(f32x4*)&Xs[row][c0]     = x0;
    *(f32x4*)&Xs[row][c0 + 4] = x1;
    __syncthreads();
#pragma unroll
    for (int k4 = 0; k4 < 8; ++k4) {
      f32x4 wv[4], xv[4];
#pragma unroll
      for (int i = 0; i < 4; ++i) wv[i] = *(const f32x4*)&Ws[j0 + i][k4 * 4];
#pragma unroll
      for (int l = 0; l < 4; ++l) xv[l] = *(const f32x4*)&Xs[b0 + l][k4 * 4];
#pragma unroll
      for (int i = 0; i < 4; ++i)
#pragma unroll
        for (int l = 0; l < 4; ++l)
          acc[i][l] += wv[i][0] * xv[l][0] + wv[i][1] * xv[l][1] +
                       wv[i][2] * xv[l][2] + wv[i][3] * xv[l][3];
    }
  }
#pragma unroll
  for (int i = 0; i < 4; ++i)
#pragma unroll
    for (int l = 0; l < 4; ++l) {
      int j = jb * 64 + j0 + i, bb = b0 + l;
      gates[(size_t)bb * 4096 + j] = acc[i][l] + hWhh[(size_t)bb * 4096 + j];
    }
}

// ---------------- K4b: LSTM pointwise -> h_new, c_new, xcat ----------------
__global__ void k4b_lstm(const float* __restrict__ gates, const float* __restrict__ cin,
                         float* __restrict__ out, unsigned short* __restrict__ xcat) {
  int b = blockIdx.x;
  for (int j = threadIdx.x; j < HID_; j += blockDim.x) {
    float ig = gates[(size_t)b * 4096 + j];
    float fg = gates[(size_t)b * 4096 + 1024 + j];
    float gg = gates[(size_t)b * 4096 + 2048 + j];
    float og = gates[(size_t)b * 4096 + 3072 + j];
    float i = 1.f / (1.f + expf(-ig));
    float f = 1.f / (1.f + expf(-fg));
    float g = tanhf(gg);
    float o = 1.f / (1.f + expf(-og));
    float c0 = cin[(size_t)b * 1024 + j];
    float cn = f * c0 + i * g;
    float hn = o * tanhf(cn);
    out[PRED_N + (size_t)b * 1024 + j] = hn;
    out[PRED_N + 65536 + (size_t)b * 1024 + j] = cn;
    xcat[b * 2560 + j] = f2bf(hn);
  }
}

// ---------------- K5: pred = xcat(bf16) @ fc_W.T + fc_b ----------------
// LDS-free streaming GEMM: each wave owns 16 vocab rows; B-fragment read
// straight from fcW (16 rows x 128B contiguous, coalesced), A-tile (4KB/step,
// shared by the block's 4 waves) via L1. No barriers; 1-deep reg prefetch.
__global__ __launch_bounds__(256) void k5_pred(
    const unsigned short* __restrict__ xcat, const float* __restrict__ fcW,
    const float* __restrict__ fcb, float* __restrict__ pred) {
  const int tid = threadIdx.x;
  const int wave = tid >> 6, lane = tid & 63;
  const int l16 = lane & 15, l4 = lane >> 4;
  const int vrow = blockIdx.x * 64 + wave * 16 + l16;   // this lane's fcW row
  const float* bg = fcW + (size_t)vrow * 2560 + l4 * 8;
  const unsigned short* ag = xcat + (size_t)l16 * 2560 + l4 * 8;

  f32x4 acc[4] = {};   // m = 0..3 -> batch rows m*16 + l4*4 + j

  f32x4 nb0 = *(const f32x4*)(bg);
  f32x4 nb1 = *(const f32x4*)(bg + 4);
  s16x8 na0 = *(const s16x8*)(ag);
  s16x8 na1 = *(const s16x8*)(ag + 16 * 2560);
  s16x8 na2 = *(const s16x8*)(ag + 32 * 2560);
  s16x8 na3 = *(const s16x8*)(ag + 48 * 2560);

  for (int kt = 0; kt < 80; ++kt) {
    f32x4 b0 = nb0, b1 = nb1;
    s16x8 a0 = na0, a1 = na1, a2 = na2, a3 = na3;
    if (kt < 79) {
      bg += 32; ag += 32;
      nb0 = *(const f32x4*)(bg);
      nb1 = *(const f32x4*)(bg + 4);
      na0 = *(const s16x8*)(ag);
      na1 = *(const s16x8*)(ag + 16 * 2560);
      na2 = *(const s16x8*)(ag + 32 * 2560);
      na3 = *(const s16x8*)(ag + 48 * 2560);
    }
    s16x8 bv = pack8(b0, b1);
    acc[0] = __builtin_amdgcn_mfma_f32_16x16x32_bf16(a0, bv, acc[0], 0, 0, 0);
    acc[1] = __builtin_amdgcn_mfma_f32_16x16x32_bf16(a1, bv, acc[1], 0, 0, 0);
    acc[2] = __builtin_amdgcn_mfma_f32_16x16x32_bf16(a2, bv, acc[2], 0, 0, 0);
    acc[3] = __builtin_amdgcn_mfma_f32_16x16x32_bf16(a3, bv, acc[3], 0, 0, 0);
  }

  float fb = fcb[vrow];
#pragma unroll
  for (int m = 0; m < 4; ++m)
#pragma unroll
    for (int j = 0; j < 4; ++j)
      pred[(size_t)(m * 16 + l4 * 4 + j) * VSZ_ + vrow] = acc[m][j] + fb;
}

extern "C" void kernel_launch(void* const* d_in, const int* in_sizes, int n_in,
                              void* d_out, int out_size, void* d_ws, size_t ws_size,
                              hipStream_t stream) {
  (void)in_sizes; (void)n_in; (void)out_size; (void)ws_size;
  const int*   tok   = (const int*)  d_in[0];
  const float* h     = (const float*)d_in[1];
  const float* c     = (const float*)d_in[2];
  const float* enc   = (const float*)d_in[3];
  const float* emb   = (const float*)d_in[4];
  const float* attnW = (const float*)d_in[5];
  const float* attnb = (const float*)d_in[6];
  const float* vW    = (const float*)d_in[7];
  const float* Wih   = (const float*)d_in[8];
  const float* Whh   = (const float*)d_in[9];
  const float* bih   = (const float*)d_in[10];
  const float* bhh   = (const float*)d_in[11];
  const float* fcW   = (const float*)d_in[12];
  const float* fcb   = (const float*)d_in[13];
  float* out = (float*)d_out;

  float* scores  = (float*)d_ws;                 // 32768
  float* weights = scores + 32768;               // 32768
  float* hW      = weights + 32768;              // 64*1024
  float* hWhh    = hW + 64 * 1024;               // 64*4096
  float* x2      = hWhh + 64 * 4096;             // 64*1536  [e | ctx]
  float* gates   = x2 + 64 * 1536;               // 64*4096
  unsigned short* xcat = (unsigned short*)(gates + 64 * 4096);  // 64*2560 bf16

  hipMemsetAsync(scores, 0, 32768 * sizeof(float), stream);
  k1a_emb<<<64, 128, 0, stream>>>(tok, emb, x2, xcat);
  k1_rowdot<<<dim3(64, 64), 256, 0, stream>>>(attnW, 2048, attnb, nullptr, h, hW, 1024);
  k1_rowdot<<<dim3(256, 64), 256, 0, stream>>>(Whh, 1024, bih, bhh, h, hWhh, 4096);
  k2_scores<<<dim3(256, 8), 256, 0, stream>>>(enc, attnW, hW, vW, scores);
  k3a_softmax<<<64, 64, 0, stream>>>(scores, weights);
  k3b_ctx<<<256, 256, 0, stream>>>(weights, enc, x2, xcat);
  k4_gates<<<64, 256, 0, stream>>>(x2, Wih, hWhh, gates);
  k4b_lstm<<<64, 256, 0, stream>>>(gates, c, out, xcat);
  k5_pred<<<500, 256, 0, stream>>>(xcat, fcW, fcb, out);
}